// Round 3
// baseline (4003.666 us; speedup 1.0000x reference)
//
#include <hip/hip_runtime.h>
#include <hip/hip_bf16.h>
#include <math.h>

// ---------------- constants ----------------
#define Vv 32000
#define Dd 768
#define Ee 768
#define Hh 12
#define Bb 4
#define Ss 512
#define EPSf 1e-5f

typedef unsigned short u16;

struct __align__(8) us4 { u16 x, y, z, w; };

__device__ __forceinline__ float b2f(u16 v) {
    union { unsigned u; float f; } x; x.u = ((unsigned)v) << 16; return x.f;
}
__device__ __forceinline__ u16 f2b(float f) {
    union { float f; unsigned u; } x; x.f = f;
    unsigned u = x.u;
    unsigned r = (u + 0x7FFFu + ((u >> 16) & 1u)) >> 16;
    return (u16)r;
}

__device__ __forceinline__ void load4(const float* p, float v[4]) {
    float4 q = *(const float4*)p; v[0]=q.x; v[1]=q.y; v[2]=q.z; v[3]=q.w;
}
__device__ __forceinline__ void load4(const u16* p, float v[4]) {
    us4 q = *(const us4*)p; v[0]=b2f(q.x); v[1]=b2f(q.y); v[2]=b2f(q.z); v[3]=b2f(q.w);
}
__device__ __forceinline__ void store1(float* p, float v) { *p = v; }
__device__ __forceinline__ void store1(u16* p, float v)   { *p = f2b(v); }

// ---------------- reductions ----------------
__device__ __forceinline__ float waveReduceSum(float v) {
    #pragma unroll
    for (int o = 32; o > 0; o >>= 1) v += __shfl_down(v, o, 64);
    return v;
}
__device__ __forceinline__ float waveReduceMax(float v) {
    #pragma unroll
    for (int o = 32; o > 0; o >>= 1) v = fmaxf(v, __shfl_down(v, o, 64));
    return v;
}
__device__ __forceinline__ float blockReduceSum(float v) {
    __shared__ float red[4];
    v = waveReduceSum(v);
    __syncthreads();
    if ((threadIdx.x & 63) == 0) red[threadIdx.x >> 6] = v;
    __syncthreads();
    return red[0] + red[1] + red[2] + red[3];
}
__device__ __forceinline__ float blockReduceMax(float v) {
    __shared__ float red[4];
    v = waveReduceMax(v);
    __syncthreads();
    if ((threadIdx.x & 63) == 0) red[threadIdx.x >> 6] = v;
    __syncthreads();
    return fmaxf(fmaxf(red[0], red[1]), fmaxf(red[2], red[3]));
}

__device__ __forceinline__ float gelu_exact(float x) {
    return 0.5f * x * (1.0f + erff(x * 0.70710678118654752f));
}

// ---------------- generic tiled GEMM ----------------
// C[M,N] = alpha * A[M,K] @ (TB_T ? B[N,K]^T : B[K,N]) (+ bias)(+ gelu)
// batched over blockIdx.z: z0 = z % zmod, z1 = z / zmod
#define BM 64
#define BN 64
#define BK 16

template<typename TA, typename TB, typename TC, int EPI, bool TB_T>
__global__ __launch_bounds__(256)
void gemm_kernel(const TA* __restrict__ A, const TB* __restrict__ Bm,
                 const float* __restrict__ bias, TC* __restrict__ C,
                 int M, int N, int K, int lda, int ldb, int ldc, float alpha,
                 int zmod,
                 long long sA0, long long sA1, long long sB0, long long sB1,
                 long long sC0, long long sC1, long long sb0, long long sb1)
{
    int z = blockIdx.z;
    int z0 = z % zmod, z1 = z / zmod;
    A  += (size_t)z0 * sA0 + (size_t)z1 * sA1;
    Bm += (size_t)z0 * sB0 + (size_t)z1 * sB1;
    C  += (size_t)z0 * sC0 + (size_t)z1 * sC1;
    if (bias) bias += (size_t)z0 * sb0 + (size_t)z1 * sb1;

    __shared__ float As[BK][BM + 4];
    __shared__ float Bs[BK][BN + 4];

    const int t  = threadIdx.x;
    const int tx = t & 15, ty = t >> 4;
    const int m0 = blockIdx.y * BM, n0 = blockIdx.x * BN;

    const int arow = t >> 2, avec = t & 3;      // A loader: 64 rows x (4 k-chunks)
    const int brow = t >> 4, bcol4 = t & 15;    // B NN loader: 16 k-rows x 16 col-chunks

    float acc[4][4] = {};

    for (int kt = 0; kt < K; kt += BK) {
        float av[4], bv[4];
        load4(A + (size_t)(m0 + arow) * lda + kt + avec * 4, av);
        if (TB_T) {
            load4(Bm + (size_t)(n0 + arow) * ldb + kt + avec * 4, bv);
        } else {
            load4(Bm + (size_t)(kt + brow) * ldb + n0 + bcol4 * 4, bv);
        }
        __syncthreads();
        #pragma unroll
        for (int j = 0; j < 4; j++) As[avec * 4 + j][arow] = av[j];
        if (TB_T) {
            #pragma unroll
            for (int j = 0; j < 4; j++) Bs[avec * 4 + j][arow] = bv[j];
        } else {
            *(float4*)&Bs[brow][bcol4 * 4] = make_float4(bv[0], bv[1], bv[2], bv[3]);
        }
        __syncthreads();
        #pragma unroll
        for (int kk = 0; kk < BK; kk++) {
            float4 a4 = *(const float4*)&As[kk][ty * 4];
            float4 b4 = *(const float4*)&Bs[kk][tx * 4];
            float a[4] = {a4.x, a4.y, a4.z, a4.w};
            float b[4] = {b4.x, b4.y, b4.z, b4.w};
            #pragma unroll
            for (int i = 0; i < 4; i++)
                #pragma unroll
                for (int j = 0; j < 4; j++)
                    acc[i][j] = fmaf(a[i], b[j], acc[i][j]);
        }
    }

    #pragma unroll
    for (int i = 0; i < 4; i++) {
        int row = m0 + ty * 4 + i;
        #pragma unroll
        for (int j = 0; j < 4; j++) {
            int col = n0 + tx * 4 + j;
            float v = acc[i][j] * alpha;
            if (EPI >= 1) v += bias[col];
            if (EPI == 2) v = gelu_exact(v);
            store1(C + (size_t)row * ldc + col, v);
        }
    }
}

// ---------------- embed + LN (fp32 inputs -> bf16 X) ----------------
__global__ __launch_bounds__(256)
void embed_ln_kernel(const int* __restrict__ ids, const float* __restrict__ tok,
                     const float* __restrict__ seg, const float* __restrict__ g,
                     const float* __restrict__ be, u16* __restrict__ X)
{
    int r = blockIdx.x;            // r = b*S + s
    int s = r & (Ss - 1);
    int id = ids[r];
    int sg = (s >= Ss / 2 + 1) ? 1 : 0;
    float vals[3];
    #pragma unroll
    for (int c = 0; c < 3; c++) {
        int d = threadIdx.x + c * 256;
        float expo = -(2.0f * (float)d / (float)Dd) * 9.2103403719761836f; // ln(10000)
        float ang = (float)s * expf(expo);
        float pos = (d & 1) ? cosf(ang) : sinf(ang);
        vals[c] = tok[(size_t)id * Dd + d] + seg[(size_t)sg * Dd + d] + pos;
    }
    float sum = blockReduceSum(vals[0] + vals[1] + vals[2]);
    float mean = sum / (float)Dd;
    float vs = 0.f;
    #pragma unroll
    for (int c = 0; c < 3; c++) { float dlt = vals[c] - mean; vs += dlt * dlt; }
    vs = blockReduceSum(vs);
    float rstd = rsqrtf(vs / (float)Dd + EPSf);
    #pragma unroll
    for (int c = 0; c < 3; c++) {
        int d = threadIdx.x + c * 256;
        X[(size_t)r * Dd + d] = f2b((vals[c] - mean) * rstd * g[d] + be[d]);
    }
}

// ---------------- LN (fp32 src -> bf16 dst) ----------------
__global__ __launch_bounds__(256)
void ln_kernel(const float* __restrict__ src, const float* __restrict__ g,
               const float* __restrict__ be, u16* __restrict__ dst)
{
    int r = blockIdx.x;
    float vals[3];
    #pragma unroll
    for (int c = 0; c < 3; c++) vals[c] = src[(size_t)r * Dd + threadIdx.x + c * 256];
    float sum = blockReduceSum(vals[0] + vals[1] + vals[2]);
    float mean = sum / (float)Dd;
    float vs = 0.f;
    #pragma unroll
    for (int c = 0; c < 3; c++) { float dlt = vals[c] - mean; vs += dlt * dlt; }
    vs = blockReduceSum(vs);
    float rstd = rsqrtf(vs / (float)Dd + EPSf);
    #pragma unroll
    for (int c = 0; c < 3; c++) {
        int d = threadIdx.x + c * 256;
        dst[(size_t)r * Dd + d] = f2b((vals[c] - mean) * rstd * g[d] + be[d]);
    }
}

// ---------------- masked softmax over t (row len 512), in-place bf16 ----------------
__global__ __launch_bounds__(256)
void softmax_kernel(u16* __restrict__ scores, const unsigned char* __restrict__ mask)
{
    int row = blockIdx.x;          // row = (b*H + h)*S + s
    int z = row >> 9;              // b*H + h
    int s = row & (Ss - 1);
    int b = z / Hh;
    u16* sp = scores + (size_t)row * Ss;
    const unsigned char* mp = mask + ((size_t)(b * Ss + s)) * Ss;
    float v[2];
    #pragma unroll
    for (int c = 0; c < 2; c++) {
        int d = threadIdx.x + c * 256;
        v[c] = mp[d] ? -1e9f : b2f(sp[d]);
    }
    float mx = blockReduceMax(fmaxf(v[0], v[1]));
    float e[2]; e[0] = expf(v[0] - mx); e[1] = expf(v[1] - mx);
    float sum = blockReduceSum(e[0] + e[1]);
    float inv = 1.0f / sum;
    #pragma unroll
    for (int c = 0; c < 2; c++) {
        int d = threadIdx.x + c * 256;
        sp[d] = f2b(e[c] * inv);
    }
}

// ---------------- in-place log-softmax over V (fp32) ----------------
__global__ __launch_bounds__(256)
void logsoftmax_kernel(float* __restrict__ out)
{
    int row = blockIdx.x;
    size_t base = (size_t)row * Vv;
    float mx = -1e30f;
    for (int i = threadIdx.x; i < Vv; i += 256) mx = fmaxf(mx, out[base + i]);
    mx = blockReduceMax(mx);
    float s = 0.f;
    for (int i = threadIdx.x; i < Vv; i += 256) s += expf(out[base + i] - mx);
    s = blockReduceSum(s);
    float lse = logf(s);
    for (int i = threadIdx.x; i < Vv; i += 256) {
        out[base + i] = out[base + i] - mx - lse;
    }
}

// ---------------- cls head (fp32 out) ----------------
__global__ __launch_bounds__(64)
void cls_kernel(const u16* __restrict__ enc, const float* __restrict__ Wc,
                const float* __restrict__ bc, float* __restrict__ out)
{
    int idx = blockIdx.x;          // 0..7 : b*2 + j
    int b = idx >> 1, j = idx & 1;
    float s = 0.f;
    for (int d = threadIdx.x; d < Dd; d += 64)
        s += b2f(enc[((size_t)b * Ss) * Dd + d]) * Wc[d * 2 + j];
    s = waveReduceSum(s);
    if (threadIdx.x == 0)
        out[(size_t)Bb * Ss * Vv + idx] = s + bc[j];
}

// ---------------- launch ----------------
extern "C" void kernel_launch(void* const* d_in, const int* in_sizes, int n_in,
                              void* d_out, int out_size, void* d_ws, size_t ws_size,
                              hipStream_t stream)
{
    const int* ids            = (const int*)d_in[0];
    const unsigned char* mask = (const unsigned char*)d_in[1];
    const float* tok   = (const float*)d_in[2];
    const float* seg   = (const float*)d_in[3];
    const float* g_emb = (const float*)d_in[4];
    const float* b_emb = (const float*)d_in[5];
    const float* Wq    = (const float*)d_in[6];
    const float* bq    = (const float*)d_in[7];
    const float* Wk    = (const float*)d_in[8];
    const float* bk    = (const float*)d_in[9];
    const float* Wv    = (const float*)d_in[10];
    const float* bv    = (const float*)d_in[11];
    const float* Wo    = (const float*)d_in[12];
    const float* bo    = (const float*)d_in[13];
    const float* g_at  = (const float*)d_in[14];
    const float* b_at  = (const float*)d_in[15];
    const float* W1    = (const float*)d_in[16];
    const float* b1    = (const float*)d_in[17];
    const float* W2    = (const float*)d_in[18];
    const float* b2    = (const float*)d_in[19];
    const float* g_ff  = (const float*)d_in[20];
    const float* b_ff  = (const float*)d_in[21];
    const float* Wp    = (const float*)d_in[22];
    const float* bp    = (const float*)d_in[23];
    const float* Wc    = (const float*)d_in[24];
    const float* bc    = (const float*)d_in[25];

    char* ws = (char*)d_ws;
    size_t off = 0;
    auto alloc = [&](size_t bytes) { void* p = ws + off; off += (bytes + 255) & ~(size_t)255; return p; };

    u16*   X      = (u16*)  alloc((size_t)Bb*Ss*Dd*2);           // 3.1 MB
    u16*   q      = (u16*)  alloc((size_t)Bb*Hh*Ss*Ee*2);        // 37.7 MB
    u16*   k      = (u16*)  alloc((size_t)Bb*Hh*Ss*Ee*2);
    u16*   v      = (u16*)  alloc((size_t)Bb*Hh*Ss*Ee*2);
    u16*   sc     = (u16*)  alloc((size_t)Bb*Hh*Ss*Ss*2);        // 25.2 MB (scores, softmaxed in-place)
    u16*   ctxc   = (u16*)  alloc((size_t)Bb*Ss*Hh*Ee*2);        // 37.7 MB
    float* t1     = (float*)alloc((size_t)Bb*Ss*Dd*4);           // 6.3 MB
    u16*   attn_o = (u16*)  alloc((size_t)Bb*Ss*Dd*2);
    u16*   h1     = (u16*)  alloc((size_t)Bb*Ss*Dd*2);
    float* t2     = (float*)alloc((size_t)Bb*Ss*Dd*4);
    u16*   enc    = (u16*)  alloc((size_t)Bb*Ss*Dd*2);
    (void)ws_size; (void)in_sizes; (void)n_in; (void)out_size;

    float* outp = (float*)d_out;   // fp32 output: [B*S, V] log-softmax + 8 cls floats

    // 1. embedding + LN -> X (bf16)
    embed_ln_kernel<<<Bb*Ss, 256, 0, stream>>>(ids, tok, seg, g_emb, b_emb, X);

    // 2. QKV projections: per (b,h): [512,768] @ [768,768] + bias
    const long long SD = (long long)Ss*Dd, DE = (long long)Dd*Ee, SE = (long long)Ss*Ee;
    dim3 gqkv(Ee/BN, Ss/BM, Bb*Hh);
    gemm_kernel<u16,float,u16,1,false><<<gqkv, 256, 0, stream>>>(
        X, Wq, bq, q, Ss, Ee, Dd, Dd, Ee, Ee, 1.0f,
        Bb, SD, 0, 0, DE, (long long)Hh*SE, SE, 0, Ee);
    gemm_kernel<u16,float,u16,1,false><<<gqkv, 256, 0, stream>>>(
        X, Wk, bk, k, Ss, Ee, Dd, Dd, Ee, Ee, 1.0f,
        Bb, SD, 0, 0, DE, (long long)Hh*SE, SE, 0, Ee);
    gemm_kernel<u16,float,u16,1,false><<<gqkv, 256, 0, stream>>>(
        X, Wv, bv, v, Ss, Ee, Dd, Dd, Ee, Ee, 1.0f,
        Bb, SD, 0, 0, DE, (long long)Hh*SE, SE, 0, Ee);

    // 3. scores = q @ k^T / sqrt(S)  (NT GEMM, bf16 out)
    dim3 gsc(Ss/BN, Ss/BM, Bb*Hh);
    gemm_kernel<u16,u16,u16,0,true><<<gsc, 256, 0, stream>>>(
        q, k, nullptr, sc, Ss, Ss, Ee, Ee, Ee, Ss, 0.044194173824159216f,
        1, 0, SE, 0, SE, 0, (long long)Ss*Ss, 0, 0);

    // 4. mask + softmax in-place on sc (bf16)
    softmax_kernel<<<Bb*Hh*Ss, 256, 0, stream>>>(sc, mask);

    // 5. ctx = attn @ v, written concat-transposed: ctxc[b, s, h*E+e]
    dim3 gctx(Ee/BN, Ss/BM, Bb*Hh);
    gemm_kernel<u16,u16,u16,0,false><<<gctx, 256, 0, stream>>>(
        sc, v, nullptr, ctxc, Ss, Ee, Ss, Ss, Ee, Hh*Ee, 1.0f,
        Hh, (long long)Ss*Ss, (long long)Hh*Ss*Ss, SE, (long long)Hh*SE,
        Ee, (long long)Ss*Hh*Ee, 0, 0);

    // 6. t1 = ctxc @ Wo + bo (fp32) ; LN -> attn_o
    dim3 gwo(Dd/BN, (Bb*Ss)/BM, 1);
    gemm_kernel<u16,float,float,1,false><<<gwo, 256, 0, stream>>>(
        ctxc, Wo, bo, t1, Bb*Ss, Dd, Hh*Ee, Hh*Ee, Dd, Dd, 1.0f,
        1, 0,0,0,0,0,0,0,0);
    ln_kernel<<<Bb*Ss, 256, 0, stream>>>(t1, g_at, b_at, attn_o);

    // 7. h1 = gelu(attn_o @ W1 + b1) (bf16)
    gemm_kernel<u16,float,u16,2,false><<<gwo, 256, 0, stream>>>(
        attn_o, W1, b1, h1, Bb*Ss, Ee, Dd, Dd, Ee, Ee, 1.0f,
        1, 0,0,0,0,0,0,0,0);

    // 8. t2 = h1 @ W2 + b2 (fp32) ; LN -> enc
    gemm_kernel<u16,float,float,1,false><<<gwo, 256, 0, stream>>>(
        h1, W2, b2, t2, Bb*Ss, Dd, Ee, Ee, Dd, Dd, 1.0f,
        1, 0,0,0,0,0,0,0,0);
    ln_kernel<<<Bb*Ss, 256, 0, stream>>>(t2, g_ff, b_ff, enc);

    // 9. logits = enc @ Wp + bp -> d_out (fp32), then in-place log-softmax
    dim3 gwp(Vv/BN, (Bb*Ss)/BM, 1);
    gemm_kernel<u16,float,float,1,false><<<gwp, 256, 0, stream>>>(
        enc, Wp, bp, outp, Bb*Ss, Vv, Dd, Dd, Vv, Vv, 1.0f,
        1, 0,0,0,0,0,0,0,0);
    logsoftmax_kernel<<<Bb*Ss, 256, 0, stream>>>(outp);

    // 10. cls head -> last 8 outputs (fp32)
    cls_kernel<<<Bb*2, 64, 0, stream>>>(enc, Wc, bc, outp);
}